// Round 2
// baseline (242.682 us; speedup 1.0000x reference)
//
#include <hip/hip_runtime.h>
#include <cstdint>

#define TOPK_K 10
#define NCLS   80
#define EPS_F     1e-8f
#define IOU_EPS_F 1e-7f
#define CH 64   // anchors per k_align block

typedef unsigned long long u64;

// ---------------------------------------------------------------------------
// k_prep: detect gt_mask dtype (bool/u8 vs int32), expand to int gmask[B*M],
// zero pos_align/pos_iou.
// ---------------------------------------------------------------------------
__global__ void k_prep(const unsigned char* __restrict__ gm, int n,
                       int* __restrict__ gmask,
                       unsigned int* __restrict__ pos_a,
                       unsigned int* __restrict__ pos_i)
{
    __shared__ int anynz;
    if (threadIdx.x == 0) anynz = 0;
    __syncthreads();
    for (int i = threadIdx.x; i < n; i += blockDim.x) {
        if ((i & 3) && gm[i]) anynz = 1;   // benign race
    }
    __syncthreads();
    const int is_int32 = (anynz == 0);
    const int* gi = (const int*)gm;
    for (int i = threadIdx.x; i < n; i += blockDim.x) {
        gmask[i] = is_int32 ? (gi[i] != 0) : (gm[i] != 0);
        pos_a[i] = 0u;
        pos_i[i] = 0u;
    }
}

// ---------------------------------------------------------------------------
// k_align: one block per (b, 64-anchor chunk). Stage 64x80 score tile in LDS
// (padded to 81), each thread owns one anchor, sweeps m. Coalesced everywhere.
// Also zeroes mask_bits for its anchors.
// ---------------------------------------------------------------------------
__global__ __launch_bounds__(256) void k_align(
    const float*  __restrict__ ps,    // (B,A,C)
    const float4* __restrict__ pb,    // (B,A,4)
    const float2* __restrict__ apts,  // (A,2)
    const int*    __restrict__ gl,    // (B,M)
    const float4* __restrict__ gb,    // (B,M,4)
    const int*    __restrict__ gmask, // (B,M)
    float*        __restrict__ align, // (B,M,A)
    u64*          __restrict__ mask_bits, // (B,A)
    int B, int A, int C, int M, int NCH)
{
    const int blk = blockIdx.x;
    const int b  = blk / NCH;
    const int ch = blk - b * NCH;
    const int a0 = ch * CH;
    const int aN = min(CH, A - a0);
    const int tid = threadIdx.x;

    __shared__ float  ssc[CH][81];
    __shared__ float4 sgb[64];
    __shared__ int    scls[64];
    __shared__ int    sgm[64];

    if (tid < aN) mask_bits[(size_t)b * A + a0 + tid] = 0ull;
    if (tid < M) {
        sgb[tid]  = gb[b * M + tid];
        scls[tid] = gl[b * M + tid];
        sgm[tid]  = gmask[b * M + tid];
    }

    const int C4 = C >> 2;  // 20
    const float4* psrow = (const float4*)(ps + ((size_t)b * A + a0) * C);
    for (int idx = tid; idx < aN * C4; idx += 256) {
        const int r  = idx / C4;
        const int c4 = idx - r * C4;
        const float4 v = psrow[(size_t)r * C4 + c4];
        float* dst = &ssc[r][c4 * 4];
        dst[0] = v.x; dst[1] = v.y; dst[2] = v.z; dst[3] = v.w;
    }
    __syncthreads();

    const int asub = tid & (CH - 1);
    const int m0   = tid >> 6;          // 0..3, uniform per wave
    const bool act = (asub < aN);
    float2 an = make_float2(0.f, 0.f);
    float4 p  = make_float4(0.f, 0.f, 0.f, 0.f);
    float areap = 0.f;
    if (act) {
        an = apts[a0 + asub];
        p  = pb[(size_t)b * A + a0 + asub];
        areap = (p.z - p.x) * (p.w - p.y);
    }
    for (int m = m0; m < M; m += 4) {
        if (!act) continue;
        float al = 0.f;
        if (sgm[m]) {
            const float4 g = sgb[m];
            const float d = fminf(fminf(an.x - g.x, an.y - g.y),
                                  fminf(g.z - an.x, g.w - an.y));
            if (d > EPS_F) {
                const float iw = fmaxf(fminf(g.z, p.z) - fmaxf(g.x, p.x), 0.f);
                const float ih = fmaxf(fminf(g.w, p.w) - fmaxf(g.y, p.y), 0.f);
                const float inter = iw * ih;
                const float areag = (g.z - g.x) * (g.w - g.y);
                const float iou = fmaxf(inter / (areag + areap - inter + IOU_EPS_F), 0.f);
                const float sc = ssc[asub][scls[m]];
                const float i2 = iou * iou;
                al = sc * (i2 * i2 * i2);   // score * iou^6, same assoc as before
            }
        }
        align[((size_t)b * M + m) * A + a0 + asub] = al;
    }
}

// ---------------------------------------------------------------------------
// k_topk2: one block per (b,m). Coalesced float4 scan of the align row,
// register-resident top-10 as packed u64 keys (value desc, index asc),
// 10 rounds of shuffle-butterfly block argmax. No scratch, no runtime idx.
// ---------------------------------------------------------------------------
#define INS10(val, idx)                                                     \
    {                                                                       \
        u64 key = ((u64)__float_as_uint(val) << 32) |                       \
                  (unsigned)(~(unsigned)(idx));                             \
        if (key > kk[9]) {                                                  \
            _Pragma("unroll")                                               \
            for (int q = 0; q < 10; ++q) {                                  \
                if (key > kk[q]) { u64 t_ = kk[q]; kk[q] = key; key = t_; } \
            }                                                               \
        }                                                                   \
    }

__global__ __launch_bounds__(256) void k_topk2(
    const float4* __restrict__ align4,
    const float2* __restrict__ apts,
    const int*    __restrict__ gmask,
    const float4* __restrict__ gb,
    u64*          __restrict__ mask_bits,
    int B, int A, int M)
{
    const int bm = blockIdx.x;
    if (!gmask[bm]) return;
    const int b = bm / M;
    const int m = bm - b * M;
    const int tid = threadIdx.x;

    const float4 g = gb[bm];
    const float4* row = align4 + (size_t)bm * (A >> 2);
    const int n4 = A >> 2;

    u64 kk[10];
#pragma unroll
    for (int q = 0; q < 10; ++q) kk[q] = 0ull;

    for (int i = tid; i < n4; i += 256) {
        const float4 v = row[i];
        const int a4 = i * 4;
        INS10(v.x, a4 + 0);
        INS10(v.y, a4 + 1);
        INS10(v.z, a4 + 2);
        INS10(v.w, a4 + 3);
    }

    __shared__ u64 swv[4];
    const u64 bit = 1ull << m;
    for (int r = 0; r < TOPK_K; ++r) {
        u64 cur = kk[0];
#pragma unroll
        for (int off = 32; off; off >>= 1) {
            const u64 o = __shfl_xor(cur, off);
            cur = (o > cur) ? o : cur;
        }
        if ((tid & 63) == 0) swv[tid >> 6] = cur;
        __syncthreads();
        const u64 w01 = (swv[0] > swv[1]) ? swv[0] : swv[1];
        const u64 w23 = (swv[2] > swv[3]) ? swv[2] : swv[3];
        const u64 win = (w01 > w23) ? w01 : w23;
        if (kk[0] == win) {   // unique owner pops (index makes keys unique)
#pragma unroll
            for (int q = 0; q < 9; ++q) kk[q] = kk[q + 1];
            kk[9] = 0ull;
        }
        if (tid == 0) {
            const unsigned a = ~(unsigned)(win & 0xFFFFFFFFull);
            const float2 an = apts[a];
            const float d = fminf(fminf(an.x - g.x, an.y - g.y),
                                  fminf(g.z - an.x, g.w - an.y));
            if (d > EPS_F)
                atomicOr(&mask_bits[(size_t)b * A + a], bit);
        }
        __syncthreads();
    }
}

// ---------------------------------------------------------------------------
// k_resolve2: per anchor — fg, multi-assignment via argmax IoU, pos atomics,
// labels/boxes/fg outputs. aval read from align buffer (no ps gather).
// ---------------------------------------------------------------------------
__global__ __launch_bounds__(256) void k_resolve2(
    const float*  __restrict__ align,
    const float4* __restrict__ pb,
    const float2* __restrict__ apts,
    const int*    __restrict__ gl,
    const float4* __restrict__ gb,
    const int*    __restrict__ gmask,
    const u64*    __restrict__ mask_bits,
    int*          __restrict__ assign,
    float*        __restrict__ aval,
    unsigned int* __restrict__ pos_align,
    unsigned int* __restrict__ pos_iou,
    float*        __restrict__ out,
    int B, int A, int C, int M)
{
    const int id = blockIdx.x * blockDim.x + threadIdx.x;
    if (id >= B * A) return;
    const int b = id / A;
    const int a = id - b * A;

    const u64 bits = mask_bits[id];
    const int cnt = __popcll(bits);
    int t = 0, fg = 0;
    const float2 an = apts[a];
    const float4 p  = pb[id];
    const float areap = (p.z - p.x) * (p.w - p.y);

    if (cnt == 1) {
        t = __ffsll(bits) - 1; fg = 1;
    } else if (cnt > 1) {
        float best = -1.0f; int bi = 0;
        for (int mm = 0; mm < M; ++mm) {
            const float4 gg = gb[b * M + mm];
            const float d = fminf(fminf(an.x - gg.x, an.y - gg.y),
                                  fminf(gg.z - an.x, gg.w - an.y));
            float iou = 0.0f;
            if (d > EPS_F && gmask[b * M + mm]) {
                const float iw = fmaxf(fminf(gg.z, p.z) - fmaxf(gg.x, p.x), 0.0f);
                const float ih = fmaxf(fminf(gg.w, p.w) - fmaxf(gg.y, p.y), 0.0f);
                const float inter = iw * ih;
                const float areag = (gg.z - gg.x) * (gg.w - gg.y);
                iou = fmaxf(inter / (areag + areap - inter + IOU_EPS_F), 0.0f);
            }
            if (iou > best) { best = iou; bi = mm; }
        }
        t = bi; fg = 1;
    }

    float av = 0.0f;
    if (fg) {
        av = align[((size_t)b * M + t) * A + a];
        const float4 gg = gb[b * M + t];
        const float d = fminf(fminf(an.x - gg.x, an.y - gg.y),
                              fminf(gg.z - an.x, gg.w - an.y));
        if (d > EPS_F && gmask[b * M + t]) {
            const float iw = fmaxf(fminf(gg.z, p.z) - fmaxf(gg.x, p.x), 0.0f);
            const float ih = fmaxf(fminf(gg.w, p.w) - fmaxf(gg.y, p.y), 0.0f);
            const float inter = iw * ih;
            const float areag = (gg.z - gg.x) * (gg.w - gg.y);
            const float iou = fmaxf(inter / (areag + areap - inter + IOU_EPS_F), 0.0f);
            if (av  > 0.0f) atomicMax(&pos_align[b * M + t], __float_as_uint(av));
            if (iou > 0.0f) atomicMax(&pos_iou[b * M + t],  __float_as_uint(iou));
        }
    }

    assign[id] = t;
    aval[id]   = av;

    int lab = gl[b * M + t];
    lab = lab < 0 ? 0 : (lab > NCLS ? NCLS : lab);
    out[id] = (float)lab;                                   // target_labels
    ((float4*)(out + (size_t)B * A))[id] = gb[b * M + t];   // target_boxes
    out[(size_t)B * A * (5 + C) + id] = fg ? 1.0f : 0.0f;   // fg mask
}

// ---------------------------------------------------------------------------
// k_scores2: fused norm + one-hot scores write (coalesced float4).
// ---------------------------------------------------------------------------
__global__ void k_scores2(const int* __restrict__ assign,
                          const float* __restrict__ aval,
                          const unsigned int* __restrict__ pos_align,
                          const unsigned int* __restrict__ pos_iou,
                          const int* __restrict__ gl,
                          float4* __restrict__ scores,
                          int BA, int A, int M, int C4)
{
    const int gid = blockIdx.x * blockDim.x + threadIdx.x;
    if (gid >= BA * C4) return;
    const int row = gid / C4;
    const int c4  = gid - row * C4;
    const int b   = row / A;
    const int t   = assign[row];
    const float av = aval[row];
    const float pa = __uint_as_float(pos_align[b * M + t]);
    const float pi = __uint_as_float(pos_iou[b * M + t]);
    const float nv = av * pi / (pa + EPS_F);
    int lab = gl[b * M + t];
    lab = lab < 0 ? 0 : (lab > NCLS ? NCLS : lab);
    const int cb = c4 * 4;
    float4 v;
    v.x = (cb + 0 == lab) ? nv : 0.0f;
    v.y = (cb + 1 == lab) ? nv : 0.0f;
    v.z = (cb + 2 == lab) ? nv : 0.0f;
    v.w = (cb + 3 == lab) ? nv : 0.0f;
    scores[gid] = v;
}

// ===========================================================================
// Fallback path (round-1 kernels, used only if ws_size is too small for align)
// ===========================================================================
__global__ __launch_bounds__(256) void k_topk_fb(
    const float*  __restrict__ ps, const float4* __restrict__ pb,
    const float2* __restrict__ apts, const int* __restrict__ gl,
    const float4* __restrict__ gb, const int* __restrict__ gmask,
    u64* __restrict__ mask_bits, int B, int A, int C, int M)
{
    const int bm = blockIdx.x;
    if (!gmask[bm]) return;
    const int b = bm / M;
    const int m = bm - b * M;
    const float4 g = gb[bm];
    const float areag = (g.z - g.x) * (g.w - g.y);
    const int cls = gl[bm];
    const float*  psb = ps + (size_t)b * A * C + cls;
    const float4* pbb = pb + (size_t)b * A;
    const int tid = threadIdx.x;

    u64 kk[10];
#pragma unroll
    for (int q = 0; q < 10; ++q) kk[q] = 0ull;

    for (int a = tid; a < A; a += 256) {
        const float2 an = apts[a];
        const float d = fminf(fminf(an.x - g.x, an.y - g.y),
                              fminf(g.z - an.x, g.w - an.y));
        float al = 0.0f;
        if (d > EPS_F) {
            const float4 p = pbb[a];
            const float iw = fmaxf(fminf(g.z, p.z) - fmaxf(g.x, p.x), 0.0f);
            const float ih = fmaxf(fminf(g.w, p.w) - fmaxf(g.y, p.y), 0.0f);
            const float inter = iw * ih;
            const float areap = (p.z - p.x) * (p.w - p.y);
            const float iou = fmaxf(inter / (areag + areap - inter + IOU_EPS_F), 0.0f);
            const float sc = psb[(size_t)a * C];
            const float i2 = iou * iou;
            al = sc * (i2 * i2 * i2);
        }
        INS10(al, a);
    }

    __shared__ u64 swv[4];
    const u64 bit = 1ull << m;
    for (int r = 0; r < TOPK_K; ++r) {
        u64 cur = kk[0];
#pragma unroll
        for (int off = 32; off; off >>= 1) {
            const u64 o = __shfl_xor(cur, off);
            cur = (o > cur) ? o : cur;
        }
        if ((tid & 63) == 0) swv[tid >> 6] = cur;
        __syncthreads();
        const u64 w01 = (swv[0] > swv[1]) ? swv[0] : swv[1];
        const u64 w23 = (swv[2] > swv[3]) ? swv[2] : swv[3];
        const u64 win = (w01 > w23) ? w01 : w23;
        if (kk[0] == win) {
#pragma unroll
            for (int q = 0; q < 9; ++q) kk[q] = kk[q + 1];
            kk[9] = 0ull;
        }
        if (tid == 0) {
            const unsigned a = ~(unsigned)(win & 0xFFFFFFFFull);
            const float2 an = apts[a];
            const float d = fminf(fminf(an.x - g.x, an.y - g.y),
                                  fminf(g.z - an.x, g.w - an.y));
            if (d > EPS_F)
                atomicOr(&mask_bits[(size_t)b * A + a], bit);
        }
        __syncthreads();
    }
}

__global__ __launch_bounds__(256) void k_resolve_fb(
    const float*  __restrict__ ps, const float4* __restrict__ pb,
    const float2* __restrict__ apts, const int* __restrict__ gl,
    const float4* __restrict__ gb, const int* __restrict__ gmask,
    const u64* __restrict__ mask_bits,
    int* __restrict__ assign, float* __restrict__ aval,
    unsigned int* __restrict__ pos_align, unsigned int* __restrict__ pos_iou,
    float* __restrict__ out, int B, int A, int C, int M)
{
    const int id = blockIdx.x * blockDim.x + threadIdx.x;
    if (id >= B * A) return;
    const int b = id / A;
    const int a = id - b * A;
    const u64 bits = mask_bits[id];
    const int cnt = __popcll(bits);
    int t = 0, fg = 0;
    const float2 an = apts[a];
    const float4 p  = pb[id];
    const float areap = (p.z - p.x) * (p.w - p.y);
    if (cnt == 1) { t = __ffsll(bits) - 1; fg = 1; }
    else if (cnt > 1) {
        float best = -1.0f; int bi = 0;
        for (int mm = 0; mm < M; ++mm) {
            const float4 gg = gb[b * M + mm];
            const float d = fminf(fminf(an.x - gg.x, an.y - gg.y),
                                  fminf(gg.z - an.x, gg.w - an.y));
            float iou = 0.0f;
            if (d > EPS_F && gmask[b * M + mm]) {
                const float iw = fmaxf(fminf(gg.z, p.z) - fmaxf(gg.x, p.x), 0.0f);
                const float ih = fmaxf(fminf(gg.w, p.w) - fmaxf(gg.y, p.y), 0.0f);
                const float inter = iw * ih;
                const float areag = (gg.z - gg.x) * (gg.w - gg.y);
                iou = fmaxf(inter / (areag + areap - inter + IOU_EPS_F), 0.0f);
            }
            if (iou > best) { best = iou; bi = mm; }
        }
        t = bi; fg = 1;
    }
    float av = 0.0f;
    if (fg) {
        const float4 gg = gb[b * M + t];
        const float d = fminf(fminf(an.x - gg.x, an.y - gg.y),
                              fminf(gg.z - an.x, gg.w - an.y));
        if (d > EPS_F && gmask[b * M + t]) {
            const float iw = fmaxf(fminf(gg.z, p.z) - fmaxf(gg.x, p.x), 0.0f);
            const float ih = fmaxf(fminf(gg.w, p.w) - fmaxf(gg.y, p.y), 0.0f);
            const float inter = iw * ih;
            const float areag = (gg.z - gg.x) * (gg.w - gg.y);
            const float iou = fmaxf(inter / (areag + areap - inter + IOU_EPS_F), 0.0f);
            const float sc = ps[((size_t)b * A + a) * C + gl[b * M + t]];
            const float i2 = iou * iou;
            av = sc * (i2 * i2 * i2);
            if (av  > 0.0f) atomicMax(&pos_align[b * M + t], __float_as_uint(av));
            if (iou > 0.0f) atomicMax(&pos_iou[b * M + t],  __float_as_uint(iou));
        }
    }
    assign[id] = t;
    aval[id]   = av;
    int lab = gl[b * M + t];
    lab = lab < 0 ? 0 : (lab > NCLS ? NCLS : lab);
    out[id] = (float)lab;
    ((float4*)(out + (size_t)B * A))[id] = gb[b * M + t];
    out[(size_t)B * A * (5 + C) + id] = fg ? 1.0f : 0.0f;
}

__global__ void k_zero64(u64* __restrict__ p, int n)
{
    const int id = blockIdx.x * blockDim.x + threadIdx.x;
    if (id < n) p[id] = 0ull;
}

extern "C" void kernel_launch(void* const* d_in, const int* in_sizes, int n_in,
                              void* d_out, int out_size, void* d_ws, size_t ws_size,
                              hipStream_t stream)
{
    const float*  ps = (const float*)d_in[0];
    const float4* pb = (const float4*)d_in[1];
    const float2* ap = (const float2*)d_in[2];
    const int*    gl = (const int*)d_in[3];
    const float4* gb = (const float4*)d_in[4];
    const unsigned char* gm = (const unsigned char*)d_in[5];

    const int A = in_sizes[2] / 2;
    const int B = in_sizes[1] / (A * 4);
    const int M = in_sizes[4] / (B * 4);
    const int C = in_sizes[0] / (B * A);
    const int BA = B * A;
    const int C4 = C / 4;

    size_t off = 0;
    auto alloc = [&](size_t bytes) {
        void* p = (char*)d_ws + off;
        off += (bytes + 255) & ~(size_t)255;
        return p;
    };
    u64*   mask_bits = (u64*)alloc((size_t)BA * 8);
    unsigned int* pos_a = (unsigned int*)alloc((size_t)B * M * 4);
    unsigned int* pos_i = (unsigned int*)alloc((size_t)B * M * 4);
    int*   gmask  = (int*)alloc((size_t)B * M * 4);
    int*   assign = (int*)alloc((size_t)BA * 4);
    float* aval   = (float*)alloc((size_t)BA * 4);
    float* align  = (float*)alloc((size_t)BA * M * 4);
    const bool big_ws = (off <= ws_size);

    float* out = (float*)d_out;

    k_prep<<<1, 256, 0, stream>>>(gm, B * M, gmask, pos_a, pos_i);

    if (big_ws) {
        const int NCH = (A + CH - 1) / CH;
        k_align<<<B * NCH, 256, 0, stream>>>(ps, pb, ap, gl, gb, gmask,
                                             align, mask_bits, B, A, C, M, NCH);
        k_topk2<<<B * M, 256, 0, stream>>>((const float4*)align, ap, gmask, gb,
                                           mask_bits, B, A, M);
        k_resolve2<<<(BA + 255) / 256, 256, 0, stream>>>(
            align, pb, ap, gl, gb, gmask, mask_bits,
            assign, aval, pos_a, pos_i, out, B, A, C, M);
    } else {
        k_zero64<<<(BA + 255) / 256, 256, 0, stream>>>(mask_bits, BA);
        k_topk_fb<<<B * M, 256, 0, stream>>>(ps, pb, ap, gl, gb, gmask,
                                             mask_bits, B, A, C, M);
        k_resolve_fb<<<(BA + 255) / 256, 256, 0, stream>>>(
            ps, pb, ap, gl, gb, gmask, mask_bits,
            assign, aval, pos_a, pos_i, out, B, A, C, M);
    }

    const int tot = BA * C4;
    k_scores2<<<(tot + 255) / 256, 256, 0, stream>>>(
        assign, aval, pos_a, pos_i, gl,
        (float4*)(out + (size_t)BA * 5), BA, A, M, C4);
}

// Round 3
// 205.906 us; speedup vs baseline: 1.1786x; 1.1786x over previous
//
#include <hip/hip_runtime.h>
#include <cstdint>

#define TOPK_K 10
#define NCLS   80
#define EPS_F     1e-8f
#define IOU_EPS_F 1e-7f

typedef unsigned long long u64;

// sorted-desc register top-10 insert; key = (f32 bits << 32) | ~idx
// (value desc, index asc == jax.lax.top_k tie-break). val >= 0 always here.
#define INS10(val, idx)                                                     \
    {                                                                       \
        u64 key = ((u64)__float_as_uint(val) << 32) |                       \
                  (unsigned)(~(unsigned)(idx));                             \
        if (key > kk[9]) {                                                  \
            _Pragma("unroll")                                               \
            for (int q = 0; q < 10; ++q) {                                  \
                if (key > kk[q]) { u64 t_ = kk[q]; kk[q] = key; key = t_; } \
            }                                                               \
        }                                                                   \
    }

// ---------------------------------------------------------------------------
// k_init: grid-stride zero of mask_bits; block 0 additionally detects gt_mask
// dtype (bool/u8 vs int32), expands to gmask[B*M], zeroes pos arrays.
// ---------------------------------------------------------------------------
__global__ void k_init(const unsigned char* __restrict__ gm, int n,
                       int* __restrict__ gmask,
                       unsigned int* __restrict__ pos_a,
                       unsigned int* __restrict__ pos_i,
                       u64* __restrict__ mask_bits, int BA)
{
    const int stride = gridDim.x * blockDim.x;
    for (int i = blockIdx.x * blockDim.x + threadIdx.x; i < BA; i += stride)
        mask_bits[i] = 0ull;

    if (blockIdx.x == 0) {
        __shared__ int anynz;
        if (threadIdx.x == 0) anynz = 0;
        __syncthreads();
        for (int i = threadIdx.x; i < n; i += blockDim.x) {
            if ((i & 3) && gm[i]) anynz = 1;   // benign race
        }
        __syncthreads();
        const int is_int32 = (anynz == 0);
        const int* gi = (const int*)gm;
        for (int i = threadIdx.x; i < n; i += blockDim.x) {
            gmask[i] = is_int32 ? (gi[i] != 0) : (gm[i] != 0);
            pos_a[i] = 0u;
            pos_i[i] = 0u;
        }
    }
}

// ---------------------------------------------------------------------------
// k_topk_geo: one block per (b,m). Enumerate ONLY the in-box lattice cells of
// the 3 anchor levels (8400 = 80^2 + 40^2 + 20^2, strides 8/16/32); anchor
// coords computed analytically as (j+0.5)*s (bit-exact vs input grid).
// Zero-tie exactness: seed pool with the 10 lowest-index out-of-box anchors
// (always found within a=0..63). Winners set bit m iff in-box (d > EPS).
// ---------------------------------------------------------------------------
__global__ __launch_bounds__(256) void k_topk_geo(
    const float*  __restrict__ ps,    // (B,A,C)
    const float4* __restrict__ pb,    // (B,A,4)
    const int*    __restrict__ gl,    // (B,M)
    const float4* __restrict__ gb,    // (B,M,4)
    const int*    __restrict__ gmask, // (B,M)
    u64*          __restrict__ mask_bits, // (B,A)
    int B, int A, int C, int M)
{
    const int bm = blockIdx.x;
    if (!gmask[bm]) return;
    const int b = bm / M;
    const int m = bm - b * M;
    const int tid = threadIdx.x;

    const float4 g = gb[bm];
    const float areag = (g.z - g.x) * (g.w - g.y);
    const int cls = gl[bm];
    const float*  psb = ps + (size_t)b * A * C + cls;
    const float4* pbb = pb + (size_t)b * A;

    u64 kk[10];
#pragma unroll
    for (int q = 0; q < 10; ++q) kk[q] = 0ull;

    // ---- seed: 10 lowest-index out-of-box anchors (from a = 0..63, level 0 row 0)
    if (tid < 64) {
        const float x = (tid + 0.5f) * 8.0f;
        const float y = 4.0f;
        const float d = fminf(fminf(x - g.x, y - g.y),
                              fminf(g.z - x, g.w - y));
        const u64 inb  = __ballot(d > EPS_F);
        const u64 outb = ~inb;
        if (((outb >> tid) & 1ull) &&
            __popcll(outb & ((1ull << tid) - 1ull)) < TOPK_K) {
            INS10(0.0f, tid);
        }
    }

    // ---- rect scan per level (unrolled; exact d>EPS filter inside)
#define LEVEL(SS, NN, BASE)                                                   \
    {                                                                         \
        const float s_ = (float)(SS); const int n_ = (NN);                    \
        const int jlo = max(0,      (int)floorf(g.x / s_ - 0.5f));            \
        const int jhi = min(n_ - 1, (int)ceilf (g.z / s_ - 0.5f));            \
        const int ilo = max(0,      (int)floorf(g.y / s_ - 0.5f));            \
        const int ihi = min(n_ - 1, (int)ceilf (g.w / s_ - 0.5f));            \
        const int nx = jhi - jlo + 1, ny = ihi - ilo + 1;                     \
        const int tot = (nx > 0 && ny > 0) ? nx * ny : 0;                     \
        for (int c = tid; c < tot; c += 256) {                                \
            const int ci = c / nx, cj = c - ci * nx;                          \
            const int i = ilo + ci, j = jlo + cj;                             \
            const float x = (j + 0.5f) * s_, y = (i + 0.5f) * s_;             \
            const float d = fminf(fminf(x - g.x, y - g.y),                    \
                                  fminf(g.z - x, g.w - y));                   \
            if (d > EPS_F) {                                                  \
                const int a = (BASE) + i * n_ + j;                            \
                const float4 p = pbb[a];                                      \
                const float iw = fmaxf(fminf(g.z, p.z) - fmaxf(g.x, p.x), 0.f);\
                const float ih = fmaxf(fminf(g.w, p.w) - fmaxf(g.y, p.y), 0.f);\
                const float inter = iw * ih;                                  \
                const float areap = (p.z - p.x) * (p.w - p.y);                \
                const float iou = fmaxf(inter / (areag + areap - inter + IOU_EPS_F), 0.f); \
                const float sc = psb[(size_t)a * C];                          \
                const float i2 = iou * iou;                                   \
                const float al = sc * (i2 * i2 * i2);                         \
                INS10(al, a);                                                 \
            }                                                                 \
        }                                                                     \
    }
    LEVEL(8,  80, 0)
    LEVEL(16, 40, 6400)
    LEVEL(32, 20, 8000)
#undef LEVEL

    // ---- block merge: 10 rounds of shuffle-butterfly argmax + pop
    __shared__ u64 swv[4];
    const u64 bit = 1ull << m;
    for (int r = 0; r < TOPK_K; ++r) {
        u64 cur = kk[0];
#pragma unroll
        for (int off = 32; off; off >>= 1) {
            const u64 o = __shfl_xor(cur, off);
            cur = (o > cur) ? o : cur;
        }
        if ((tid & 63) == 0) swv[tid >> 6] = cur;
        __syncthreads();
        const u64 w01 = (swv[0] > swv[1]) ? swv[0] : swv[1];
        const u64 w23 = (swv[2] > swv[3]) ? swv[2] : swv[3];
        const u64 win = (w01 > w23) ? w01 : w23;
        if (kk[0] == win) {   // unique owner pops (keys unique by index)
#pragma unroll
            for (int q = 0; q < 9; ++q) kk[q] = kk[q + 1];
            kk[9] = 0ull;
        }
        if (tid == 0 && win != 0ull) {
            const unsigned a = ~(unsigned)(win & 0xFFFFFFFFull);
            float x, y;
            if (a < 6400u) {
                const unsigned i = a / 80u, j = a - i * 80u;
                x = (j + 0.5f) * 8.0f;  y = (i + 0.5f) * 8.0f;
            } else if (a < 8000u) {
                const unsigned rr = a - 6400u;
                const unsigned i = rr / 40u, j = rr - i * 40u;
                x = (j + 0.5f) * 16.0f; y = (i + 0.5f) * 16.0f;
            } else {
                const unsigned rr = a - 8000u;
                const unsigned i = rr / 20u, j = rr - i * 20u;
                x = (j + 0.5f) * 32.0f; y = (i + 0.5f) * 32.0f;
            }
            const float d = fminf(fminf(x - g.x, y - g.y),
                                  fminf(g.z - x, g.w - y));
            if (d > EPS_F)
                atomicOr(&mask_bits[(size_t)b * A + a], bit);
        }
        __syncthreads();
    }
}

// ---------------------------------------------------------------------------
// k_topk_fb: exact full-row sweep fallback (used when A != 8400).
// ---------------------------------------------------------------------------
__global__ __launch_bounds__(256) void k_topk_fb(
    const float*  __restrict__ ps, const float4* __restrict__ pb,
    const float2* __restrict__ apts, const int* __restrict__ gl,
    const float4* __restrict__ gb, const int* __restrict__ gmask,
    u64* __restrict__ mask_bits, int B, int A, int C, int M)
{
    const int bm = blockIdx.x;
    if (!gmask[bm]) return;
    const int b = bm / M;
    const int m = bm - b * M;
    const float4 g = gb[bm];
    const float areag = (g.z - g.x) * (g.w - g.y);
    const int cls = gl[bm];
    const float*  psb = ps + (size_t)b * A * C + cls;
    const float4* pbb = pb + (size_t)b * A;
    const int tid = threadIdx.x;

    u64 kk[10];
#pragma unroll
    for (int q = 0; q < 10; ++q) kk[q] = 0ull;

    for (int a = tid; a < A; a += 256) {
        const float2 an = apts[a];
        const float d = fminf(fminf(an.x - g.x, an.y - g.y),
                              fminf(g.z - an.x, g.w - an.y));
        float al = 0.0f;
        if (d > EPS_F) {
            const float4 p = pbb[a];
            const float iw = fmaxf(fminf(g.z, p.z) - fmaxf(g.x, p.x), 0.0f);
            const float ih = fmaxf(fminf(g.w, p.w) - fmaxf(g.y, p.y), 0.0f);
            const float inter = iw * ih;
            const float areap = (p.z - p.x) * (p.w - p.y);
            const float iou = fmaxf(inter / (areag + areap - inter + IOU_EPS_F), 0.0f);
            const float sc = psb[(size_t)a * C];
            const float i2 = iou * iou;
            al = sc * (i2 * i2 * i2);
        }
        INS10(al, a);
    }

    __shared__ u64 swv[4];
    const u64 bit = 1ull << m;
    for (int r = 0; r < TOPK_K; ++r) {
        u64 cur = kk[0];
#pragma unroll
        for (int off = 32; off; off >>= 1) {
            const u64 o = __shfl_xor(cur, off);
            cur = (o > cur) ? o : cur;
        }
        if ((tid & 63) == 0) swv[tid >> 6] = cur;
        __syncthreads();
        const u64 w01 = (swv[0] > swv[1]) ? swv[0] : swv[1];
        const u64 w23 = (swv[2] > swv[3]) ? swv[2] : swv[3];
        const u64 win = (w01 > w23) ? w01 : w23;
        if (kk[0] == win) {
#pragma unroll
            for (int q = 0; q < 9; ++q) kk[q] = kk[q + 1];
            kk[9] = 0ull;
        }
        if (tid == 0 && win != 0ull) {
            const unsigned a = ~(unsigned)(win & 0xFFFFFFFFull);
            const float2 an = apts[a];
            const float d = fminf(fminf(an.x - g.x, an.y - g.y),
                                  fminf(g.z - an.x, g.w - an.y));
            if (d > EPS_F)
                atomicOr(&mask_bits[(size_t)b * A + a], bit);
        }
        __syncthreads();
    }
}

// ---------------------------------------------------------------------------
// k_resolve: per anchor — fast path when no bits set (95%); else fg,
// multi-assignment via first-max IoU, align recompute, pos atomics, outputs.
// ---------------------------------------------------------------------------
__global__ __launch_bounds__(256) void k_resolve(
    const float*  __restrict__ ps,
    const float4* __restrict__ pb,
    const float2* __restrict__ apts,
    const int*    __restrict__ gl,
    const float4* __restrict__ gb,
    const int*    __restrict__ gmask,
    const u64*    __restrict__ mask_bits,
    int*          __restrict__ assign,
    float*        __restrict__ aval,
    unsigned int* __restrict__ pos_align,
    unsigned int* __restrict__ pos_iou,
    float*        __restrict__ out,
    int B, int A, int C, int M)
{
    const int id = blockIdx.x * blockDim.x + threadIdx.x;
    if (id >= B * A) return;
    const int b = id / A;
    const int a = id - b * A;

    const u64 bits = mask_bits[id];

    if (bits == 0ull) {   // background: no gathers needed
        assign[id] = 0;
        aval[id]   = 0.0f;
        int lab = gl[b * M];
        lab = lab < 0 ? 0 : (lab > NCLS ? NCLS : lab);
        out[id] = (float)lab;
        ((float4*)(out + (size_t)B * A))[id] = gb[b * M];
        out[(size_t)B * A * (5 + NCLS) + id] = 0.0f;
        return;
    }

    const int cnt = __popcll(bits);
    int t;
    const float2 an = apts[a];
    const float4 p  = pb[id];
    const float areap = (p.z - p.x) * (p.w - p.y);

    if (cnt == 1) {
        t = __ffsll(bits) - 1;
    } else {
        float best = -1.0f; int bi = 0;
        for (int mm = 0; mm < M; ++mm) {
            const float4 gg = gb[b * M + mm];
            const float d = fminf(fminf(an.x - gg.x, an.y - gg.y),
                                  fminf(gg.z - an.x, gg.w - an.y));
            float iou = 0.0f;
            if (d > EPS_F && gmask[b * M + mm]) {
                const float iw = fmaxf(fminf(gg.z, p.z) - fmaxf(gg.x, p.x), 0.0f);
                const float ih = fmaxf(fminf(gg.w, p.w) - fmaxf(gg.y, p.y), 0.0f);
                const float inter = iw * ih;
                const float areag = (gg.z - gg.x) * (gg.w - gg.y);
                iou = fmaxf(inter / (areag + areap - inter + IOU_EPS_F), 0.0f);
            }
            if (iou > best) { best = iou; bi = mm; }
        }
        t = bi;
    }

    float av = 0.0f;
    {
        const float4 gg = gb[b * M + t];
        const float d = fminf(fminf(an.x - gg.x, an.y - gg.y),
                              fminf(gg.z - an.x, gg.w - an.y));
        if (d > EPS_F && gmask[b * M + t]) {
            const float iw = fmaxf(fminf(gg.z, p.z) - fmaxf(gg.x, p.x), 0.0f);
            const float ih = fmaxf(fminf(gg.w, p.w) - fmaxf(gg.y, p.y), 0.0f);
            const float inter = iw * ih;
            const float areag = (gg.z - gg.x) * (gg.w - gg.y);
            const float iou = fmaxf(inter / (areag + areap - inter + IOU_EPS_F), 0.0f);
            const float sc = ps[((size_t)b * A + a) * C + gl[b * M + t]];
            const float i2 = iou * iou;
            av = sc * (i2 * i2 * i2);
            if (av  > 0.0f) atomicMax(&pos_align[b * M + t], __float_as_uint(av));
            if (iou > 0.0f) atomicMax(&pos_iou[b * M + t],  __float_as_uint(iou));
        }
    }

    assign[id] = t;
    aval[id]   = av;

    int lab = gl[b * M + t];
    lab = lab < 0 ? 0 : (lab > NCLS ? NCLS : lab);
    out[id] = (float)lab;                                   // target_labels
    ((float4*)(out + (size_t)B * A))[id] = gb[b * M + t];   // target_boxes
    out[(size_t)B * A * (5 + NCLS) + id] = 1.0f;            // fg mask
}

// ---------------------------------------------------------------------------
// k_scores2: fused norm + one-hot scores write (coalesced float4).
// ---------------------------------------------------------------------------
__global__ void k_scores2(const int* __restrict__ assign,
                          const float* __restrict__ aval,
                          const unsigned int* __restrict__ pos_align,
                          const unsigned int* __restrict__ pos_iou,
                          const int* __restrict__ gl,
                          float4* __restrict__ scores,
                          int BA, int A, int M, int C4)
{
    const int gid = blockIdx.x * blockDim.x + threadIdx.x;
    if (gid >= BA * C4) return;
    const int row = gid / C4;
    const int c4  = gid - row * C4;
    const int b   = row / A;
    const int t   = assign[row];
    const float av = aval[row];
    const float pa = __uint_as_float(pos_align[b * M + t]);
    const float pi = __uint_as_float(pos_iou[b * M + t]);
    const float nv = av * pi / (pa + EPS_F);
    int lab = gl[b * M + t];
    lab = lab < 0 ? 0 : (lab > NCLS ? NCLS : lab);
    const int cb = c4 * 4;
    float4 v;
    v.x = (cb + 0 == lab) ? nv : 0.0f;
    v.y = (cb + 1 == lab) ? nv : 0.0f;
    v.z = (cb + 2 == lab) ? nv : 0.0f;
    v.w = (cb + 3 == lab) ? nv : 0.0f;
    scores[gid] = v;
}

extern "C" void kernel_launch(void* const* d_in, const int* in_sizes, int n_in,
                              void* d_out, int out_size, void* d_ws, size_t ws_size,
                              hipStream_t stream)
{
    const float*  ps = (const float*)d_in[0];
    const float4* pb = (const float4*)d_in[1];
    const float2* ap = (const float2*)d_in[2];
    const int*    gl = (const int*)d_in[3];
    const float4* gb = (const float4*)d_in[4];
    const unsigned char* gm = (const unsigned char*)d_in[5];

    const int A = in_sizes[2] / 2;
    const int B = in_sizes[1] / (A * 4);
    const int M = in_sizes[4] / (B * 4);
    const int C = in_sizes[0] / (B * A);
    const int BA = B * A;
    const int C4 = C / 4;

    size_t off = 0;
    auto alloc = [&](size_t bytes) {
        void* p = (char*)d_ws + off;
        off += (bytes + 255) & ~(size_t)255;
        return p;
    };
    u64*   mask_bits = (u64*)alloc((size_t)BA * 8);
    unsigned int* pos_a = (unsigned int*)alloc((size_t)B * M * 4);
    unsigned int* pos_i = (unsigned int*)alloc((size_t)B * M * 4);
    int*   gmask  = (int*)alloc((size_t)B * M * 4);
    int*   assign = (int*)alloc((size_t)BA * 4);
    float* aval   = (float*)alloc((size_t)BA * 4);
    (void)off;

    float* out = (float*)d_out;

    k_init<<<128, 256, 0, stream>>>(gm, B * M, gmask, pos_a, pos_i,
                                    mask_bits, BA);

    if (A == 8400 && C == NCLS && M <= 64) {
        k_topk_geo<<<B * M, 256, 0, stream>>>(ps, pb, gl, gb, gmask,
                                              mask_bits, B, A, C, M);
    } else {
        k_topk_fb<<<B * M, 256, 0, stream>>>(ps, pb, ap, gl, gb, gmask,
                                             mask_bits, B, A, C, M);
    }

    k_resolve<<<(BA + 255) / 256, 256, 0, stream>>>(
        ps, pb, ap, gl, gb, gmask, mask_bits,
        assign, aval, pos_a, pos_i, out, B, A, C, M);

    const int tot = BA * C4;
    k_scores2<<<(tot + 255) / 256, 256, 0, stream>>>(
        assign, aval, pos_a, pos_i, gl,
        (float4*)(out + (size_t)BA * 5), BA, A, M, C4);
}